// Round 10
// baseline (158.104 us; speedup 1.0000x reference)
//
#include <hip/hip_runtime.h>
#include <hip/hip_cooperative_groups.h>
#include <hip/hip_bf16.h>

namespace cg = cooperative_groups;

#define BLOCK 256
#define GRID  2048   // exactly 8 blocks/CU x 256 CUs (16 VGPR, 512 B LDS) — co-resident

// BCE-with-logits, masked row sum, product-of-factors form:
//   loss = max(x,0) + log(1+exp(-|x|)) - x*t
// log terms accumulate multiplicatively -> one __logf per thread at the end.
// 32 elems/thread, factors in (1,2] -> prod <= 2^32, safe in f32;
// log abs-error ~2e-6, far below the 1.2e-2 threshold.
__device__ __forceinline__ void bce4(const float4 xv, const float4 tv,
                                     float& sum_lin, float& prod) {
    const bool b0 = (tv.x + tv.y) > 0.0f;   // row mask (2 cols/row)
    const bool b1 = (tv.z + tv.w) > 0.0f;
    const float m0 = b0 ? 1.0f : 0.0f;
    const float m1 = b1 ? 1.0f : 0.0f;

    const float f0 = 1.0f + __expf(-fabsf(xv.x));
    const float f1 = 1.0f + __expf(-fabsf(xv.y));
    const float f2 = 1.0f + __expf(-fabsf(xv.z));
    const float f3 = 1.0f + __expf(-fabsf(xv.w));
    prod *= b0 ? (f0 * f1) : 1.0f;
    prod *= b1 ? (f2 * f3) : 1.0f;

    const float r0 = __builtin_fmaf(-xv.x, tv.x, fmaxf(xv.x, 0.0f));
    const float r1 = __builtin_fmaf(-xv.y, tv.y, fmaxf(xv.y, 0.0f));
    const float r2 = __builtin_fmaf(-xv.z, tv.z, fmaxf(xv.z, 0.0f));
    const float r3 = __builtin_fmaf(-xv.w, tv.w, fmaxf(xv.w, 0.0f));
    sum_lin = __builtin_fmaf(m0, r0 + r1, sum_lin);
    sum_lin = __builtin_fmaf(m1, r2 + r3, sum_lin);
}

// ---- fused cooperative kernel: round-5 loop + grid.sync + round-9 tail ----
__global__ __launch_bounds__(BLOCK) void bce_coop_kernel(
        const float4* __restrict__ x4,
        const float4* __restrict__ t4,
        float* __restrict__ partials,
        float* __restrict__ out,
        int n4) {
    float sum_lin = 0.0f, prod = 1.0f;
    const int stride = GRID * BLOCK;
    for (int i = blockIdx.x * BLOCK + threadIdx.x; i < n4; i += 2 * stride) {
        bce4(x4[i], t4[i], sum_lin, prod);
        const int j = i + stride;
        if (j < n4) bce4(x4[j], t4[j], sum_lin, prod);
    }
    float sum = sum_lin + __logf(prod);   // one log per thread

    #pragma unroll
    for (int off = 32; off > 0; off >>= 1)
        sum += __shfl_down(sum, off, 64);

    __shared__ float wsum[BLOCK / 64];
    const int lane = threadIdx.x & 63;
    const int wid  = threadIdx.x >> 6;
    if (lane == 0) wsum[wid] = sum;
    __syncthreads();

    if (threadIdx.x == 0)
        partials[blockIdx.x] = wsum[0] + wsum[1] + wsum[2] + wsum[3];

    // Library grid barrier: full agent-scope release/acquire (L2 wb/inv),
    // unlike the hand-rolled atomic chain that failed in rounds 6/7.
    cg::this_grid().sync();

    if (blockIdx.x == 0 && threadIdx.x < 64) {   // wave 0 of block 0
        const float4* p4 = (const float4*)partials;
        double s = 0.0;
        #pragma unroll
        for (int k = 0; k < GRID / 4 / 64; ++k) {          // 8 float4/thread
            const float4 v = p4[threadIdx.x + k * 64];
            s += (double)v.x + (double)v.y + (double)v.z + (double)v.w;
        }
        #pragma unroll
        for (int off = 32; off > 0; off >>= 1)
            s += __shfl_down(s, off, 64);
        if (threadIdx.x == 0)
            out[0] = (float)(s * (1.0 / (double)(4 * n4)));
    }
}

// ---- verified round-9 two-kernel fallback (bit-identical output) ----
__global__ __launch_bounds__(BLOCK) void bce_partial_kernel(
        const float4* __restrict__ x4,
        const float4* __restrict__ t4,
        float* __restrict__ partials,
        int n4) {
    float sum_lin = 0.0f, prod = 1.0f;
    const int stride = gridDim.x * blockDim.x;
    for (int i = blockIdx.x * blockDim.x + threadIdx.x; i < n4; i += 2 * stride) {
        bce4(x4[i], t4[i], sum_lin, prod);
        const int j = i + stride;
        if (j < n4) bce4(x4[j], t4[j], sum_lin, prod);
    }
    float sum = sum_lin + __logf(prod);
    #pragma unroll
    for (int off = 32; off > 0; off >>= 1)
        sum += __shfl_down(sum, off, 64);
    __shared__ float wsum[BLOCK / 64];
    const int lane = threadIdx.x & 63, wid = threadIdx.x >> 6;
    if (lane == 0) wsum[wid] = sum;
    __syncthreads();
    if (threadIdx.x == 0)
        partials[blockIdx.x] = wsum[0] + wsum[1] + wsum[2] + wsum[3];
}

__global__ __launch_bounds__(64) void bce_finalize_kernel(
        const float4* __restrict__ partials4,
        float* __restrict__ out,
        double inv_n) {
    double s = 0.0;
    #pragma unroll
    for (int k = 0; k < GRID / 4 / 64; ++k) {
        const float4 v = partials4[threadIdx.x + k * 64];
        s += (double)v.x + (double)v.y + (double)v.z + (double)v.w;
    }
    #pragma unroll
    for (int off = 32; off > 0; off >>= 1)
        s += __shfl_down(s, off, 64);
    if (threadIdx.x == 0)
        out[0] = (float)(s * inv_n);
}

extern "C" void kernel_launch(void* const* d_in, const int* in_sizes, int n_in,
                              void* d_out, int out_size, void* d_ws, size_t ws_size,
                              hipStream_t stream) {
    const float4* x4 = (const float4*)d_in[0];   // inputs  [B,2] f32
    const float4* t4 = (const float4*)d_in[1];   // targets [B,2] f32
    float* out = (float*)d_out;
    float* partials = (float*)d_ws;              // 8 KB scratch

    int n4 = in_sizes[0] / 4;   // B*C divisible by 4

    void* args[] = { (void*)&x4, (void*)&t4, (void*)&partials,
                     (void*)&out, (void*)&n4 };
    hipError_t e = hipLaunchCooperativeKernel(
        (const void*)bce_coop_kernel, dim3(GRID), dim3(BLOCK),
        args, 0, stream);

    if (e != hipSuccess) {
        // Clear the error and take the verified two-kernel path
        // (same reduction order -> bit-identical output).
        (void)hipGetLastError();
        bce_partial_kernel<<<GRID, BLOCK, 0, stream>>>(x4, t4, partials, n4);
        bce_finalize_kernel<<<1, 64, 0, stream>>>(
            (const float4*)partials, out, 1.0 / (double)(4 * n4));
    }
}

// Round 11
// 28.479 us; speedup vs baseline: 5.5516x; 5.5516x over previous
//
#include <hip/hip_runtime.h>
#include <hip/hip_bf16.h>

#define BLOCK 256
#define GRID  2048   // 8 blocks/CU x 256 CUs, whole grid co-resident

// BCE-with-logits, masked row sum, product-of-factors form:
//   loss = max(x,0) + log(1+exp(-|x|)) - x*t
// log terms accumulate multiplicatively -> one __logf per thread at the end.
// 32 elems/thread, factors in (1,2] -> prod <= 2^32, safe in f32;
// log abs-error ~2e-6, far below the 1.2e-2 threshold.
//
// Structure notes (verified over rounds 3-10):
//  - two dispatches beat ANY fusion on MI355X: same-address atomics
//    serialize (~25 us), hand-rolled cross-XCD release/acquire races,
//    cg::this_grid().sync() costs ~115 us.
//  - per-block plain stores + tiny second kernel: 27.7 us, absmax 0.0.
__device__ __forceinline__ void bce4(const float4 xv, const float4 tv,
                                     float& sum_lin, float& prod) {
    const bool b0 = (tv.x + tv.y) > 0.0f;   // row mask (2 cols/row)
    const bool b1 = (tv.z + tv.w) > 0.0f;
    const float m0 = b0 ? 1.0f : 0.0f;
    const float m1 = b1 ? 1.0f : 0.0f;

    const float f0 = 1.0f + __expf(-fabsf(xv.x));
    const float f1 = 1.0f + __expf(-fabsf(xv.y));
    const float f2 = 1.0f + __expf(-fabsf(xv.z));
    const float f3 = 1.0f + __expf(-fabsf(xv.w));
    prod *= b0 ? (f0 * f1) : 1.0f;
    prod *= b1 ? (f2 * f3) : 1.0f;

    const float r0 = __builtin_fmaf(-xv.x, tv.x, fmaxf(xv.x, 0.0f));
    const float r1 = __builtin_fmaf(-xv.y, tv.y, fmaxf(xv.y, 0.0f));
    const float r2 = __builtin_fmaf(-xv.z, tv.z, fmaxf(xv.z, 0.0f));
    const float r3 = __builtin_fmaf(-xv.w, tv.w, fmaxf(xv.w, 0.0f));
    sum_lin = __builtin_fmaf(m0, r0 + r1, sum_lin);
    sum_lin = __builtin_fmaf(m1, r2 + r3, sum_lin);
}

__global__ __launch_bounds__(BLOCK) void bce_partial_kernel(
        const float4* __restrict__ x4,
        const float4* __restrict__ t4,
        float* __restrict__ partials,
        int n4) {
    float sum_lin = 0.0f, prod = 1.0f;
    const int stride = gridDim.x * blockDim.x;
    for (int i = blockIdx.x * blockDim.x + threadIdx.x; i < n4; i += 2 * stride) {
        bce4(x4[i], t4[i], sum_lin, prod);
        const int j = i + stride;
        if (j < n4) bce4(x4[j], t4[j], sum_lin, prod);
    }
    float sum = sum_lin + __logf(prod);   // one log per thread

    #pragma unroll
    for (int off = 32; off > 0; off >>= 1)
        sum += __shfl_down(sum, off, 64);

    __shared__ float wsum[BLOCK / 64];
    const int lane = threadIdx.x & 63;
    const int wid  = threadIdx.x >> 6;
    if (lane == 0) wsum[wid] = sum;
    __syncthreads();

    if (threadIdx.x == 0)
        partials[blockIdx.x] = wsum[0] + wsum[1] + wsum[2] + wsum[3];
}

// Single-wave finalize: 64 threads, no LDS, no barriers, float4 loads.
__global__ __launch_bounds__(64) void bce_finalize_kernel(
        const float4* __restrict__ partials4,
        float* __restrict__ out,
        double inv_n) {
    double s = 0.0;
    #pragma unroll
    for (int k = 0; k < GRID / 4 / 64; ++k) {          // 8 float4 per thread
        const float4 v = partials4[threadIdx.x + k * 64];
        s += (double)v.x + (double)v.y + (double)v.z + (double)v.w;
    }
    #pragma unroll
    for (int off = 32; off > 0; off >>= 1)
        s += __shfl_down(s, off, 64);

    if (threadIdx.x == 0)
        out[0] = (float)(s * inv_n);
}

extern "C" void kernel_launch(void* const* d_in, const int* in_sizes, int n_in,
                              void* d_out, int out_size, void* d_ws, size_t ws_size,
                              hipStream_t stream) {
    const float* x = (const float*)d_in[0];   // inputs  [B,2] f32
    const float* t = (const float*)d_in[1];   // targets [B,2] f32
    float* out = (float*)d_out;
    float* partials = (float*)d_ws;           // 8 KB scratch

    const int n  = in_sizes[0];   // B*C = 16777216, divisible by 4
    const int n4 = n / 4;

    bce_partial_kernel<<<GRID, BLOCK, 0, stream>>>(
        (const float4*)x, (const float4*)t, partials, n4);

    bce_finalize_kernel<<<1, 64, 0, stream>>>(
        (const float4*)partials, out, 1.0 / (double)n);
}